// Round 3
// baseline (201.370 us; speedup 1.0000x reference)
//
#include <hip/hip_runtime.h>
#include <hip/hip_bf16.h>

// PointProp for MI355X (gfx950) — R7.
//   kP: prep (Wc = W0r@Wu@Wm folded; bias chain)     kC: pack weights (bf16)
//   kD: BARRIER-FREE fused comp-sum + 4-layer MLP.
//       R6's __syncthreads (needed only for the block-shared weight LDS buf)
//       drained vmcnt every phase and compressed the 537MB comp stream into
//       pass-1 -> stream and MLP ran serially (~185us). R7 removes ALL
//       barriers: weights are double-buffered per-wave from L2 directly into
//       registers (10x16B per chunk, packed P-seq is L2-resident, 1-phase
//       prefetch); act tiles are wave-private LDS (no sync needed); comp
//       loads ride a depth-4 rolling pipeline waited only at consumption.
//       HBM streaming now spans the whole kernel; MLP hides under it.
// Math: out = L4(relu(L3(relu(L2(relu(sig@W0s^T + csum@Wc^T + bias1))))))
// with Wc = W0r@Wu@Wm folded (linearity), H padded 132->160.

typedef float  f32x4  __attribute__((ext_vector_type(4)));
typedef __bf16 bf16x8 __attribute__((ext_vector_type(8)));
typedef unsigned int   u32x2 __attribute__((ext_vector_type(2)));
typedef unsigned short u16x8 __attribute__((ext_vector_type(8)));

__device__ __forceinline__ unsigned short f2bf(float f) {
  unsigned int u = __builtin_bit_cast(unsigned int, f);
  u += 0x7fffu + ((u >> 16) & 1u);   // RNE
  return (unsigned short)(u >> 16);
}

__device__ __forceinline__ u32x2 pack4(f32x4 v) {
  u32x2 r;
  r[0] = (unsigned)f2bf(v[0]) | ((unsigned)f2bf(v[1]) << 16);
  r[1] = (unsigned)f2bf(v[2]) | ((unsigned)f2bf(v[3]) << 16);
  return r;
}

// ---------------- Kernel P: all prep (Wc, bias1, padded biases) -------------
__global__ __launch_bounds__(256) void kP(
    const float* __restrict__ W0, const float* __restrict__ Wu,
    const float* __restrict__ Wm, const float* __restrict__ bm,
    const float* __restrict__ bu, const float* __restrict__ b0,
    const float* __restrict__ b1, const float* __restrict__ b2,
    float* __restrict__ Wc, float* __restrict__ bias1,
    float* __restrict__ b1p, float* __restrict__ b2p) {
  const int b = blockIdx.x;
  const int d = threadIdx.x;
  if (b < 132) {
    __shared__ float u[256];
    const int h = b;
    float s = 0.f;
#pragma unroll 8
    for (int i = 0; i < 256; ++i) s += W0[h * 512 + 256 + i] * Wu[i * 256 + d];
    u[d] = s;
    __syncthreads();
    float s2 = 0.f;
#pragma unroll 8
    for (int j = 0; j < 256; ++j) s2 += u[j] * Wm[j * 256 + d];
    Wc[h * 256 + d] = s2;
  } else {
    __shared__ float bml[256];
    __shared__ float rbl[256];
    bml[d] = bm[d];
    __syncthreads();
    {
      const f32x4* wr = (const f32x4*)(Wu + d * 256);
      const f32x4* bm4 = (const f32x4*)bml;
      float s = 0.f;
#pragma unroll 8
      for (int i = 0; i < 64; ++i) {
        f32x4 w = wr[i], v = bm4[i];
        s += w[0] * v[0] + w[1] * v[1] + w[2] * v[2] + w[3] * v[3];
      }
      rbl[d] = 8.f * s + bu[d];
    }
    __syncthreads();
    if (d < 160) {
      float v = 0.f;
      if (d < 132) {
        float s = 0.f;
#pragma unroll 8
        for (int j = 0; j < 256; ++j) s += W0[d * 512 + 256 + j] * rbl[j];
        v = b0[d] + s;
      }
      bias1[d] = v;
      b1p[d] = (d < 132) ? b1[d] : 0.f;
      b2p[d] = (d < 132) ? b2[d] : 0.f;
    }
  }
}

// ---------------- Kernel C: pack weights to MFMA B-frag order (bf16) --------
// Chunk (kk,nt) = 1024B: lane l holds B[kk*32+(l>>4)*8+j][nt*16+(l&15)], j=0..7.
// L1: K=512,N=160; L2/L3: 160x160; L4: 160x256. P1..P4 CONTIGUOUS in ws
// (uniform chunk offset: chunk c at c*10240 for c=0..25; L4 halves at
//  266240 + h*8192).
__global__ __launch_bounds__(256) void kC(
    const float* __restrict__ W0, const float* __restrict__ Wc,
    const float* __restrict__ W1, const float* __restrict__ W2,
    const float* __restrict__ W3,
    unsigned short* __restrict__ P1, unsigned short* __restrict__ P2,
    unsigned short* __restrict__ P3, unsigned short* __restrict__ P4) {
  int e = blockIdx.x * 256 + threadIdx.x;
  if (e >= 174080) return;
  unsigned short* dst; int NT, rel, mode;
  if (e < 81920)       { dst = P1; NT = 10; rel = e;          mode = 0; }
  else if (e < 107520) { dst = P2; NT = 10; rel = e - 81920;  mode = 1; }
  else if (e < 133120) { dst = P3; NT = 10; rel = e - 107520; mode = 2; }
  else                 { dst = P4; NT = 16; rel = e - 133120; mode = 3; }
  int chunk = rel >> 9, q = rel & 511;
  int lane = q >> 3, j = q & 7;
  int kk = chunk / NT, nt = chunk - kk * NT;
  int k = kk * 32 + (lane >> 4) * 8 + j;
  int n = nt * 16 + (lane & 15);
  float v = 0.f;
  if (mode == 0) {
    if (n < 132) v = (k < 256) ? W0[n * 512 + k] : Wc[n * 256 + (k - 256)];
  } else if (mode == 1) {
    if (n < 132 && k < 132) v = W1[n * 132 + k];
  } else if (mode == 2) {
    if (n < 132 && k < 132) v = W2[n * 132 + k];
  } else {
    if (k < 132) v = W3[n * 132 + k];
  }
  dst[rel] = f2bf(v);
}

// ---- per-wave weight issue (direct L2 -> VGPR, coalesced 1KB per frag) ----
#define WISS(BUF, CHUNK)                                                     \
  {                                                                          \
    _Pragma("unroll") for (int nt = 0; nt < 10; ++nt)                        \
        BUF[nt] = *(const bf16x8*)(Pb + (CHUNK) * 10240 + nt * 1024 +        \
                                   lane * 16);                               \
  }
#define WISS8(BUF, HALF)                                                     \
  {                                                                          \
    _Pragma("unroll") for (int nt = 0; nt < 8; ++nt)                         \
        BUF[nt] = *(const bf16x8*)(Pb + 266240 + (HALF) * 8192 + nt * 1024 + \
                                   lane * 16);                               \
  }
#define MFMA10(BUF)                                                          \
  {                                                                          \
    _Pragma("unroll") for (int nt = 0; nt < 10; ++nt)                        \
        acc[nt] = __builtin_amdgcn_mfma_f32_16x16x32_bf16(af, BUF[nt],       \
                                                          acc[nt], 0, 0, 0); \
  }

// ---------------- Kernel D: barrier-free fused comp-sum + MLP ---------------
// grid 1024 x 256; wave owns 16 rows; act tile wave-private (8KB, XOR-swz).
// Weight chunks c=0..25 (10 frags) + L4 halves h=0..9 (8 frags) register-
// double-buffered, issued 1 phase ahead. comp: 64 slice-steps (8 row-pairs x
// 8 k), depth-4 pipeline, consumed in k-ascending order (matches R4 exactly).
__global__ __launch_bounds__(256, 2) void kD(
    const float* __restrict__ signal, const float* __restrict__ comp,
    const unsigned short* __restrict__ Pseq,
    const float* __restrict__ bias1, const float* __restrict__ b1p,
    const float* __restrict__ b2p, const float* __restrict__ b3,
    float* __restrict__ out) {
  extern __shared__ char lds[];
  const int tid = threadIdx.x;
  const int wave = tid >> 6;
  const int lane = tid & 63;
  const int lhalf = lane >> 4;
  const int l16 = lane & 15;
  char* act = lds + wave * 8192;
  const char* Pb = (const char*)Pseq;
  const int row0 = ((int)blockIdx.x * 4 + wave) * 16;
  const int asw = (l16 & 7) << 4;
  const int r2 = lane >> 5, c32 = lane & 31;
  const f32x4* cp = (const f32x4*)comp;
  const size_t cbase = (size_t)(row0 + r2) * 64 + c32 * 2;

  // ---- prologue: issue signal, W chunk0, comp steps 0..3 ----
  f32x4 sg[16];
  const f32x4* sp = (const f32x4*)signal;
#pragma unroll
  for (int r = 0; r < 16; ++r) sg[r] = sp[(size_t)(row0 + r) * 64 + lane];

  bf16x8 wA[10], wB[10];
  WISS(wA, 0);

  f32x4 ct[4][2];
#pragma unroll
  for (int s = 0; s < 4; ++s) {          // pair 0, k = 0..3
    ct[s][0] = cp[cbase + (size_t)s * 4194304u];
    ct[s][1] = cp[cbase + (size_t)s * 4194304u + 1];
  }

  // pack signal -> act tile (waits only the sig loads)
#pragma unroll
  for (int r = 0; r < 16; ++r)
    *(u32x2*)(act + r * 512 + ((lane * 8) ^ ((r & 7) << 4))) = pack4(sg[r]);

  f32x4 acc[10];
#pragma unroll
  for (int i = 0; i < 10; ++i) acc[i] = f32x4{0.f, 0.f, 0.f, 0.f};
  f32x4 ca0, ca1;
  u16x8 cs[8];

  // ---- L1 pass 1 (signal half), phases 0..7; comp pipeline embedded ----
#pragma unroll
  for (int kk = 0; kk < 8; ++kk) {
    if (kk & 1) { WISS(wA, kk + 1); } else { WISS(wB, kk + 1); }
#pragma unroll
    for (int i = 0; i < 8; ++i) {
      const int s = kk * 8 + i;
      const int b4 = s & 3;
      if (i == 0) { ca0 = ct[b4][0]; ca1 = ct[b4][1]; }
      else        { ca0 += ct[b4][0]; ca1 += ct[b4][1]; }
      if (s + 4 < 64) {
        const int j2 = (s + 4) >> 3, k2 = (s + 4) & 7;
        ct[b4][0] = cp[cbase + (size_t)k2 * 4194304u + j2 * 128];
        ct[b4][1] = cp[cbase + (size_t)k2 * 4194304u + j2 * 128 + 1];
      }
    }
    {
      u16x8 v;
      v[0] = f2bf(ca0[0]); v[1] = f2bf(ca0[1]);
      v[2] = f2bf(ca0[2]); v[3] = f2bf(ca0[3]);
      v[4] = f2bf(ca1[0]); v[5] = f2bf(ca1[1]);
      v[6] = f2bf(ca1[2]); v[7] = f2bf(ca1[3]);
      cs[kk] = v;
    }
    bf16x8 af =
        *(const bf16x8*)(act + l16 * 512 + ((kk * 64 + lhalf * 16) ^ asw));
    if (kk & 1) { MFMA10(wB); } else { MFMA10(wA); }
  }

  // overwrite act tile with comp-sum (wave-local; lgkmcnt-ordered)
  asm volatile("" ::: "memory");
#pragma unroll
  for (int j = 0; j < 8; ++j) {
    const int rw = 2 * j + r2;
    *(u16x8*)(act + rw * 512 + ((c32 * 16) ^ ((rw & 7) << 4))) = cs[j];
  }
  asm volatile("" ::: "memory");

  // ---- L1 pass 2 (comp-sum half), phases 8..15 (kk=15 issues L2 chunk16) --
#pragma unroll
  for (int kk = 8; kk < 16; ++kk) {
    if (kk & 1) { WISS(wA, kk + 1); } else { WISS(wB, kk + 1); }
    bf16x8 af = *(const bf16x8*)(act + l16 * 512 +
                                 (((kk - 8) * 64 + lhalf * 16) ^ asw));
    if (kk & 1) { MFMA10(wB); } else { MFMA10(wA); }
  }

  // bias + relu -> act
  {
    float bv[10];
#pragma unroll
    for (int nt = 0; nt < 10; ++nt) bv[nt] = bias1[nt * 16 + l16];
    asm volatile("" ::: "memory");
#pragma unroll
    for (int nt = 0; nt < 10; ++nt) {
#pragma unroll
      for (int r = 0; r < 4; ++r) {
        const int row = lhalf * 4 + r;
        float v = fmaxf(acc[nt][r] + bv[nt], 0.f);
        *(unsigned short*)(act + row * 512 +
                           (((nt * 16 + l16) * 2) ^ ((row & 7) << 4))) = f2bf(v);
      }
    }
    asm volatile("" ::: "memory");
  }

  // ---- hidden layers: chunks 16..20 (W1), 21..25 (W2) ----
  bf16x8 w4A[8], w4B[8];
#pragma unroll
  for (int L = 0; L < 2; ++L) {
    const float* hbias = L ? b2p : b1p;
#pragma unroll
    for (int i = 0; i < 10; ++i) acc[i] = f32x4{0.f, 0.f, 0.f, 0.f};
#pragma unroll
    for (int q = 0; q < 5; ++q) {
      const int c = 16 + L * 5 + q;        // chunk in use; parity c&1
      if (c < 25) {
        if (c & 1) { WISS(wA, c + 1); } else { WISS(wB, c + 1); }
      } else {
        WISS8(w4A, 0);                     // prefetch L4 half 0
      }
      bf16x8 af =
          *(const bf16x8*)(act + l16 * 512 + ((q * 64 + lhalf * 16) ^ asw));
      if (c & 1) { MFMA10(wB); } else { MFMA10(wA); }
    }
    float bv[10];
#pragma unroll
    for (int nt = 0; nt < 10; ++nt) bv[nt] = hbias[nt * 16 + l16];
    asm volatile("" ::: "memory");
#pragma unroll
    for (int nt = 0; nt < 10; ++nt) {
#pragma unroll
      for (int r = 0; r < 4; ++r) {
        const int row = lhalf * 4 + r;
        float v = fmaxf(acc[nt][r] + bv[nt], 0.f);
        *(unsigned short*)(act + row * 512 +
                           (((nt * 16 + l16) * 2) ^ ((row & 7) << 4))) = f2bf(v);
      }
    }
    asm volatile("" ::: "memory");
  }

  // ---- layer 4: 10 half-phases (half h: chunk h>>1, frags (h&1)*8 + i) ----
  f32x4 a4[16];
#pragma unroll
  for (int i = 0; i < 16; ++i) a4[i] = f32x4{0.f, 0.f, 0.f, 0.f};
#pragma unroll
  for (int h = 0; h < 10; ++h) {
    if (h < 9) {
      if (h & 1) { WISS8(w4A, h + 1); } else { WISS8(w4B, h + 1); }
    }
    bf16x8 af = *(const bf16x8*)(act + l16 * 512 +
                                 (((h >> 1) * 64 + lhalf * 16) ^ asw));
#pragma unroll
    for (int i = 0; i < 8; ++i) {
      const int nt = (h & 1) * 8 + i;
      if (h & 1)
        a4[nt] = __builtin_amdgcn_mfma_f32_16x16x32_bf16(af, w4B[i], a4[nt],
                                                         0, 0, 0);
      else
        a4[nt] = __builtin_amdgcn_mfma_f32_16x16x32_bf16(af, w4A[i], a4[nt],
                                                         0, 0, 0);
    }
  }

  // ---- store ----
  float bv[16];
#pragma unroll
  for (int nt = 0; nt < 16; ++nt) bv[nt] = b3[nt * 16 + l16];
  float* op = out + (size_t)(row0 + lhalf * 4) * 256 + l16;
#pragma unroll
  for (int nt = 0; nt < 16; ++nt) {
#pragma unroll
    for (int r = 0; r < 4; ++r)
      op[(size_t)r * 256 + nt * 16] = a4[nt][r] + bv[nt];
  }
}

// ---------------- launcher ----------------
extern "C" void kernel_launch(void* const* d_in, const int* in_sizes, int n_in,
                              void* d_out, int out_size, void* d_ws, size_t ws_size,
                              hipStream_t stream) {
  const float* signal = (const float*)d_in[0];
  const float* comp   = (const float*)d_in[1];
  const float* Wm = (const float*)d_in[2];
  const float* bm = (const float*)d_in[3];
  const float* Wu = (const float*)d_in[4];
  const float* bu = (const float*)d_in[5];
  const float* W0 = (const float*)d_in[6];
  const float* b0 = (const float*)d_in[7];
  const float* W1 = (const float*)d_in[8];
  const float* b1 = (const float*)d_in[9];
  const float* W2 = (const float*)d_in[10];
  const float* b2 = (const float*)d_in[11];
  const float* W3 = (const float*)d_in[12];
  const float* b3 = (const float*)d_in[13];

  char* ws = (char*)d_ws;
  float* Wc    = (float*)(ws + 0);        // 33792 f32 (135168 B)
  float* bias1 = (float*)(ws + 135168);   // 160 f32
  float* b1p   = (float*)(ws + 135808);   // 160 f32
  float* b2p   = (float*)(ws + 136448);   // 160 f32
  // contiguous packed-weight sequence (uniform chunk offsets off P1):
  unsigned short* P1 = (unsigned short*)(ws + 137216);  // 81920 u16 (160KB)
  unsigned short* P2 = (unsigned short*)(ws + 301056);  // 25600 u16 (50KB)
  unsigned short* P3 = (unsigned short*)(ws + 352256);  // 25600 u16 (50KB)
  unsigned short* P4 = (unsigned short*)(ws + 403456);  // 40960 u16 (80KB)

  hipLaunchKernelGGL(kP, dim3(133), dim3(256), 0, stream,
                     W0, Wu, Wm, bm, bu, b0, b1, b2, Wc, bias1, b1p, b2p);
  hipLaunchKernelGGL(kC, dim3(680), dim3(256), 0, stream,
                     W0, Wc, W1, W2, W3, P1, P2, P3, P4);
  hipLaunchKernelGGL(kD, dim3(1024), dim3(256), 32768, stream,
                     signal, comp, P1, bias1, b1p, b2p, b3, (float*)d_out);
}